// Round 7
// baseline (270.152 us; speedup 1.0000x reference)
//
#include <hip/hip_runtime.h>

// NodeFeatures: out = relu(x@Wu^T + bu + mask @ (x@Wv^T + bv))
// B=8, N=2048, D=128. HBM floor = 128MB mask read ~= 20us @ 6.8TB/s.
// R5: passed 232.8us; top-5 all 512MB harness poison-fills (~77us each);
// kernels < 77us each, invisible. R6: barrier-free k2 — mask A-frags loaded
// DIRECTLY from global (coalesced: 4 lanes x 32B = 2 full 64B lines/row),
// 3-deep register prefetch (rule #20: static indices), no LDS at all.
// 4x L2 mask amplification (512MB) + Vt (256MB) stays under L2 ceiling.

typedef __bf16 bf16x8 __attribute__((ext_vector_type(8)));
typedef __bf16 bf16x4 __attribute__((ext_vector_type(4)));
typedef float  f32x4  __attribute__((ext_vector_type(4)));

#define MFMA16(A, B, C) __builtin_amdgcn_mfma_f32_16x16x32_bf16(A, B, C, 0, 0, 0)

static __device__ __forceinline__ bf16x8 cvt8(const float* __restrict__ p) {
    float4 a = *(const float4*)p;
    float4 b = *(const float4*)(p + 4);
    bf16x8 v;
    v[0] = (__bf16)a.x; v[1] = (__bf16)a.y; v[2] = (__bf16)a.z; v[3] = (__bf16)a.w;
    v[4] = (__bf16)b.x; v[5] = (__bf16)b.y; v[6] = (__bf16)b.z; v[7] = (__bf16)b.w;
    return v;
}

static __device__ __forceinline__ bf16x8 pack8(const float4 a, const float4 b) {
    bf16x8 v;
    v[0] = (__bf16)a.x; v[1] = (__bf16)a.y; v[2] = (__bf16)a.z; v[3] = (__bf16)a.w;
    v[4] = (__bf16)b.x; v[5] = (__bf16)b.y; v[6] = (__bf16)b.z; v[7] = (__bf16)b.w;
    return v;
}

// ---------------------------------------------------------------------------
// Kernel 1 (unchanged): Uxb = bf16(x@Wu^T+bu); Vt[b][e][n] = bf16(x@Wv^T+bv)
// D-frag (m89-verified): col = lane&15, row = (lane>>4)*4 + reg.
// ---------------------------------------------------------------------------
__global__ __launch_bounds__(256) void k1_uv(
    const float* __restrict__ x,  const float* __restrict__ Wu,
    const float* __restrict__ bu, const float* __restrict__ Wv,
    const float* __restrict__ bv,
    __bf16* __restrict__ Uxb, __bf16* __restrict__ Vt)
{
    const int tid  = threadIdx.x;
    const int wv   = tid >> 6;
    const int lane = tid & 63;
    const int l16  = lane & 15;
    const int l4   = lane >> 4;
    const int row0 = blockIdx.x * 64;
    const int e0   = wv * 32;

    const f32x4 zero = {0.f, 0.f, 0.f, 0.f};
    f32x4 acc[4][4];
    #pragma unroll
    for (int mt = 0; mt < 4; ++mt)
        #pragma unroll
        for (int f = 0; f < 4; ++f) acc[mt][f] = zero;

    #pragma unroll
    for (int kf = 0; kf < 4; ++kf) {
        const int ko = kf * 32 + l4 * 8;
        bf16x8 af[4], bf[4];
        #pragma unroll
        for (int mt = 0; mt < 4; ++mt)
            af[mt] = cvt8(x + (size_t)(row0 + mt * 16 + l16) * 128 + ko);
        bf[0] = cvt8(Wu + (size_t)(e0 +      l16) * 128 + ko);
        bf[1] = cvt8(Wu + (size_t)(e0 + 16 + l16) * 128 + ko);
        bf[2] = cvt8(Wv + (size_t)(e0 +      l16) * 128 + ko);
        bf[3] = cvt8(Wv + (size_t)(e0 + 16 + l16) * 128 + ko);
        #pragma unroll
        for (int mt = 0; mt < 4; ++mt)
            #pragma unroll
            for (int f = 0; f < 4; ++f)
                acc[mt][f] = MFMA16(af[mt], bf[f], acc[mt][f]);
    }

    const int bidx = row0 >> 11;
    #pragma unroll
    for (int f = 0; f < 4; ++f) {
        const int e    = e0 + (f & 1) * 16 + l16;
        const bool isV = (f >= 2);
        const float bias = isV ? bv[e] : bu[e];
        #pragma unroll
        for (int mt = 0; mt < 4; ++mt) {
            if (!isV) {
                #pragma unroll
                for (int r = 0; r < 4; ++r) {
                    const int row = row0 + mt * 16 + l4 * 4 + r;
                    Uxb[(size_t)row * 128 + e] = (__bf16)(acc[mt][f][r] + bias);
                }
            } else {
                const int nbase = (row0 & 2047) + mt * 16 + l4 * 4;
                bf16x4 pk;
                #pragma unroll
                for (int r = 0; r < 4; ++r) pk[r] = (__bf16)(acc[mt][f][r] + bias);
                *(bf16x4*)(Vt + ((size_t)bidx * 128 + e) * 2048 + nbase) = pk;
            }
        }
    }
}

// ---------------------------------------------------------------------------
// Kernel 2 (R6): barrier-free, LDS-free. Each wave loads its own mask
// A-fragments directly from global (coalesced), 3-deep register prefetch
// pipeline (sets sA/sB/sC, all literal-indexed). Vt B-frags from L2 inline.
// Grid 512 (XCD-swizzled); BM=32, BK=64, 32 K-steps.
// ---------------------------------------------------------------------------
__global__ __launch_bounds__(256) void k2_agg(
    const float* __restrict__ mask,
    const __bf16* __restrict__ Vt,
    const __bf16* __restrict__ Uxb,
    float* __restrict__ out)
{
    const int bid = blockIdx.x;                   // 0..511
    const int lb  = (bid & 7) * 64 + (bid >> 3);  // bijective XCD swizzle (512 = 8*64)
    const int b   = lb >> 6;
    const int m0  = (lb & 63) * 32;

    const int tid  = threadIdx.x;
    const int wv   = tid >> 6;
    const int lane = tid & 63;
    const int l16  = lane & 15;
    const int l4   = lane >> 4;

    // A rows for this lane: mf=0 -> m0+l16, mf=1 -> m0+16+l16; k base = l4*8
    const float* r0 = mask + ((size_t)b * 2048 + m0 + l16) * 2048 + l4 * 8;
    const float* r1 = r0 + (size_t)16 * 2048;
    // B operand base for this wave/lane (Vt is [128e][2048n] per batch)
    const __bf16* vb = Vt + ((size_t)b * 128 + wv * 32 + l16) * 2048 + l4 * 8;

    const f32x4 zero = {0.f, 0.f, 0.f, 0.f};
    f32x4 acc[2][2];
    acc[0][0] = zero; acc[0][1] = zero; acc[1][0] = zero; acc[1][1] = zero;

    // prefetch sets: [0..1]=mf0/kf0, [2..3]=mf0/kf1, [4..5]=mf1/kf0, [6..7]=mf1/kf1
    float4 sA[8], sB[8], sC[8];

#define LOADSET(S, KS) {                                                      \
    const float* q0 = r0 + (size_t)(KS) * 64;                                 \
    const float* q1 = r1 + (size_t)(KS) * 64;                                 \
    S[0] = *(const float4*)(q0);      S[1] = *(const float4*)(q0 + 4);        \
    S[2] = *(const float4*)(q0 + 32); S[3] = *(const float4*)(q0 + 36);       \
    S[4] = *(const float4*)(q1);      S[5] = *(const float4*)(q1 + 4);        \
    S[6] = *(const float4*)(q1 + 32); S[7] = *(const float4*)(q1 + 36); }

#define COMPUTE(S, KS) {                                                      \
    _Pragma("unroll")                                                         \
    for (int kf = 0; kf < 2; ++kf) {                                          \
        bf16x8 af0 = pack8(S[2 * kf],     S[2 * kf + 1]);                     \
        bf16x8 af1 = pack8(S[4 + 2 * kf], S[4 + 2 * kf + 1]);                 \
        _Pragma("unroll")                                                     \
        for (int nf = 0; nf < 2; ++nf) {                                      \
            bf16x8 bfv = *(const bf16x8*)(vb + (size_t)nf * 16 * 2048         \
                                             + (KS) * 64 + kf * 32);          \
            acc[0][nf] = MFMA16(af0, bfv, acc[0][nf]);                        \
            acc[1][nf] = MFMA16(af1, bfv, acc[1][nf]);                        \
        }                                                                     \
    } }

    LOADSET(sA, 0)
    LOADSET(sB, 1)
    LOADSET(sC, 2)
    for (int t = 0; t < 10; ++t) {
        const int ks = 3 * t;
        COMPUTE(sA, ks)
        LOADSET(sA, ks + 3)                     // max 30, always valid
        COMPUTE(sB, ks + 1)
        LOADSET(sB, ks + 4)                     // max 31, always valid
        COMPUTE(sC, ks + 2)
        if (ks + 5 < 32) LOADSET(sC, ks + 5)    // skip only at t=9
    }
    COMPUTE(sA, 30)
    COMPUTE(sB, 31)
#undef LOADSET
#undef COMPUTE

    // epilogue: out = relu(acc + Ux)
    const size_t rowbase = (size_t)b * 2048 + m0;
    #pragma unroll
    for (int mf = 0; mf < 2; ++mf)
        #pragma unroll
        for (int nf = 0; nf < 2; ++nf) {
            const int e = wv * 32 + nf * 16 + l16;
            #pragma unroll
            for (int r = 0; r < 4; ++r) {
                const size_t row = rowbase + mf * 16 + l4 * 4 + r;
                const float v = acc[mf][nf][r] + (float)Uxb[row * 128 + e];
                out[row * 128 + e] = v > 0.f ? v : 0.f;
            }
        }
}

// ---------------------------------------------------------------------------
extern "C" void kernel_launch(void* const* d_in, const int* in_sizes, int n_in,
                              void* d_out, int out_size, void* d_ws, size_t ws_size,
                              hipStream_t stream) {
    (void)in_sizes; (void)n_in; (void)out_size; (void)ws_size;
    const float* x    = (const float*)d_in[0];   // [8][2048][128]
    const float* mask = (const float*)d_in[1];   // [8][2048][2048]
    const float* Wu   = (const float*)d_in[2];   // [128][128]
    const float* bu   = (const float*)d_in[3];   // [128]
    const float* Wv   = (const float*)d_in[4];   // [128][128]
    const float* bv   = (const float*)d_in[5];   // [128]
    float* out        = (float*)d_out;           // [8][2048][128] f32

    __bf16* Vt  = (__bf16*)d_ws;                 // [8][128][2048] bf16 (4MB)
    __bf16* Uxb = Vt + (size_t)8 * 128 * 2048;   // [16384][128]  bf16 (4MB)

    hipLaunchKernelGGL(k1_uv, dim3(256), dim3(256), 0, stream, x, Wu, bu, Wv, bv, Uxb, Vt);
    hipLaunchKernelGGL(k2_agg, dim3(512), dim3(256), 0, stream, mask, Vt, Uxb, out);
}